// Round 1
// baseline (2573.351 us; speedup 1.0000x reference)
//
#include <hip/hip_runtime.h>
#include <cstddef>

#define GAT_N 50000
#define GAT_E 300000

static constexpr int BM = 64, BN = 64, BK = 32;

__device__ __forceinline__ void atomicMaxF(float* addr, float v) {
    int vi = __float_as_int(v);
    if (vi >= 0) atomicMax((int*)addr, vi);
    else atomicMin((unsigned int*)addr, (unsigned int)vi);
}

// init out buffer to broadcast bias, emax to -inf, denom to 0
__global__ __launch_bounds__(256) void init_layer(
    float* __restrict__ out, const float* __restrict__ bias,
    int n, int hd, float* __restrict__ emax, float* __restrict__ denom, int nh)
{
    int stride = gridDim.x * blockDim.x;
    long tot = (long)n * hd;
    for (long i = blockIdx.x * blockDim.x + threadIdx.x; i < tot; i += stride) {
        out[i] = bias[i % hd];
        if (i < nh) { emax[i] = -__builtin_inff(); denom[i] = 0.f; }
    }
}

// feat = A(NxK) @ W(KxM); el[n,h] = sum_d feat*al, er likewise. D = M/H.
__global__ __launch_bounds__(256) void gemm_feat(
    const float* __restrict__ A, const float* __restrict__ W,
    const float* __restrict__ al, const float* __restrict__ ar,
    float* __restrict__ feat, float* __restrict__ el, float* __restrict__ er,
    int N, int K, int M, int H)
{
    __shared__ float As[BK][BM + 4];   // k-major (transposed) for float4 reads
    __shared__ float Ws[BK][BN];
    const int m0 = blockIdx.x * BM;
    const int n0 = blockIdx.y * BN;
    const int t  = threadIdx.x;
    const int tx = t & 15, ty = t >> 4;

    float acc[4][4] = {};

    for (int k0 = 0; k0 < K; k0 += BK) {
        // A tile: 64 rows x 32 k, 2 float4 per thread, coalesced
        #pragma unroll
        for (int l = 0; l < 2; ++l) {
            int i = t + l * 256;
            int row = i >> 3, kk = (i & 7) * 4;
            float4 v = make_float4(0.f, 0.f, 0.f, 0.f);
            int gr = m0 + row;
            if (gr < N) v = *(const float4*)(A + (size_t)gr * K + k0 + kk);
            As[kk + 0][row] = v.x;
            As[kk + 1][row] = v.y;
            As[kk + 2][row] = v.z;
            As[kk + 3][row] = v.w;
        }
        // W tile: 32 k x 64 n
        #pragma unroll
        for (int l = 0; l < 2; ++l) {
            int i = t + l * 256;
            int kr = i >> 4, nn = (i & 15) * 4;
            float4 v = make_float4(0.f, 0.f, 0.f, 0.f);
            int gc = n0 + nn;
            const float* wp = W + (size_t)(k0 + kr) * M + gc;
            if (gc + 3 < M) {
                v = *(const float4*)wp;
            } else {
                if (gc + 0 < M) v.x = wp[0];
                if (gc + 1 < M) v.y = wp[1];
                if (gc + 2 < M) v.z = wp[2];
            }
            *(float4*)&Ws[kr][nn] = v;
        }
        __syncthreads();
        #pragma unroll
        for (int k = 0; k < BK; ++k) {
            float av[4], bv[4];
            *(float4*)av = *(const float4*)&As[k][ty * 4];
            *(float4*)bv = *(const float4*)&Ws[k][tx * 4];
            #pragma unroll
            for (int i = 0; i < 4; ++i)
                #pragma unroll
                for (int j = 0; j < 4; ++j)
                    acc[i][j] = fmaf(av[i], bv[j], acc[i][j]);
        }
        __syncthreads();
    }

    const int D = M / H;
    const int head = n0 / D;

    // store feat
    #pragma unroll
    for (int i = 0; i < 4; ++i) {
        int gr = m0 + ty * 4 + i;
        if (gr < N) {
            int gc = n0 + tx * 4;
            if (gc + 3 < M) {
                float4 o = make_float4(acc[i][0], acc[i][1], acc[i][2], acc[i][3]);
                *(float4*)(feat + (size_t)gr * M + gc) = o;
            } else {
                #pragma unroll
                for (int j = 0; j < 4; ++j)
                    if (gc + j < M) feat[(size_t)gr * M + gc + j] = acc[i][j];
            }
        }
    }

    // el / er: reduce over the 16 tx lanes (each holds 4 cols of one head)
    #pragma unroll
    for (int i = 0; i < 4; ++i) {
        float s1 = 0.f, s2 = 0.f;
        #pragma unroll
        for (int j = 0; j < 4; ++j) {
            int gc = n0 + tx * 4 + j;
            if (gc < M) { s1 += acc[i][j] * al[gc]; s2 += acc[i][j] * ar[gc]; }
        }
        #pragma unroll
        for (int mask = 1; mask <= 8; mask <<= 1) {
            s1 += __shfl_xor(s1, mask);
            s2 += __shfl_xor(s2, mask);
        }
        int gr = m0 + ty * 4 + i;
        if (tx == 0 && gr < N) {
            el[(size_t)gr * H + head] = s1;
            er[(size_t)gr * H + head] = s2;
        }
    }
}

template<int H>
__global__ __launch_bounds__(256) void edge_scores(
    const int* __restrict__ src, const int* __restrict__ dst,
    const float* __restrict__ el, const float* __restrict__ er,
    float* __restrict__ e_out, float* __restrict__ emax, int E)
{
    int e = blockIdx.x * blockDim.x + threadIdx.x;
    if (e >= E) return;
    int s = src[e], d = dst[e];
    #pragma unroll
    for (int h = 0; h < H; ++h) {
        float v = el[(size_t)s * H + h] + er[(size_t)d * H + h];
        v = v > 0.f ? v : v * 0.2f;
        e_out[(size_t)e * H + h] = v;
        atomicMaxF(&emax[(size_t)d * H + h], v);
    }
}

template<int H>
__global__ __launch_bounds__(256) void edge_exp(
    const int* __restrict__ dst, float* __restrict__ e_io,
    const float* __restrict__ emax, float* __restrict__ denom, int E)
{
    int e = blockIdx.x * blockDim.x + threadIdx.x;
    if (e >= E) return;
    int d = dst[e];
    #pragma unroll
    for (int h = 0; h < H; ++h) {
        float x = expf(e_io[(size_t)e * H + h] - emax[(size_t)d * H + h]);
        e_io[(size_t)e * H + h] = x;
        unsafeAtomicAdd(&denom[(size_t)d * H + h], x);
    }
}

// one wave per edge; H*D = 256, lane handles float4; h = lane/16
__global__ __launch_bounds__(256) void edge_aggr256(
    const int* __restrict__ src, const int* __restrict__ dst,
    const float* __restrict__ ee, const float* __restrict__ denom,
    const float* __restrict__ feat, float* __restrict__ out, int E)
{
    int e = blockIdx.x * 4 + (threadIdx.x >> 6);
    if (e >= E) return;
    int lane = threadIdx.x & 63;
    int s = src[e], d = dst[e];
    int flat = lane * 4;
    int h = lane >> 4;
    float alpha = ee[(size_t)e * 4 + h] / fmaxf(denom[(size_t)d * 4 + h], 1e-9f);
    float4 f = *(const float4*)(feat + (size_t)s * 256 + flat);
    float* op = out + (size_t)d * 256 + flat;
    unsafeAtomicAdd(op + 0, f.x * alpha);
    unsafeAtomicAdd(op + 1, f.y * alpha);
    unsafeAtomicAdd(op + 2, f.z * alpha);
    unsafeAtomicAdd(op + 3, f.w * alpha);
}

// one wave per edge; H=1, D=47
__global__ __launch_bounds__(256) void edge_aggr47(
    const int* __restrict__ src, const int* __restrict__ dst,
    const float* __restrict__ ee, const float* __restrict__ denom,
    const float* __restrict__ feat, float* __restrict__ out, int E)
{
    int e = blockIdx.x * 4 + (threadIdx.x >> 6);
    if (e >= E) return;
    int lane = threadIdx.x & 63;
    int s = src[e], d = dst[e];
    float alpha = ee[e] / fmaxf(denom[d], 1e-9f);
    if (lane < 47)
        unsafeAtomicAdd(out + (size_t)d * 47 + lane, feat[(size_t)s * 47 + lane] * alpha);
}

extern "C" void kernel_launch(void* const* d_in, const int* in_sizes, int n_in,
                              void* d_out, int out_size, void* d_ws, size_t ws_size,
                              hipStream_t stream) {
    const float* x   = (const float*)d_in[0];
    const int*   src = (const int*)d_in[1];
    const int*   dst = (const int*)d_in[2];
    const float* W1  = (const float*)d_in[3];
    const float* al1 = (const float*)d_in[4];
    const float* ar1 = (const float*)d_in[5];
    const float* b1  = (const float*)d_in[6];
    const float* W2  = (const float*)d_in[7];
    const float* al2 = (const float*)d_in[8];
    const float* ar2 = (const float*)d_in[9];
    const float* b2  = (const float*)d_in[10];
    const float* W3  = (const float*)d_in[11];
    const float* al3 = (const float*)d_in[12];
    const float* ar3 = (const float*)d_in[13];
    const float* b3  = (const float*)d_in[14];
    float* out = (float*)d_out;

    const int N = GAT_N, E = GAT_E;

    float* ws = (float*)d_ws;
    size_t o = 0;
    float* F     = ws + o; o += (size_t)N * 256;   // feat buffer
    float* Abuf  = ws + o; o += (size_t)N * 256;   // h ping-pong / out accum
    float* el    = ws + o; o += (size_t)N * 4;
    float* er    = ws + o; o += (size_t)N * 4;
    float* emax  = ws + o; o += (size_t)N * 4;
    float* denom = ws + o; o += (size_t)N * 4;
    float* est   = ws + o; o += (size_t)E * 4;     // e then ee, [E,H]

    dim3 blk(256);
    int gE = (E + 255) / 256;
    int gEw = (E + 3) / 4;
    dim3 gemmG(( N + BM - 1) / BM, 4);

    // ---- layer 1: x[ N,128] -> Abuf[N,256]
    init_layer<<<2048, blk, 0, stream>>>(Abuf, b1, N, 256, emax, denom, N * 4);
    gemm_feat<<<gemmG, blk, 0, stream>>>(x, W1, al1, ar1, F, el, er, N, 128, 256, 4);
    edge_scores<4><<<gE, blk, 0, stream>>>(src, dst, el, er, est, emax, E);
    edge_exp<4><<<gE, blk, 0, stream>>>(dst, est, emax, denom, E);
    edge_aggr256<<<gEw, blk, 0, stream>>>(src, dst, est, denom, F, Abuf, E);

    // ---- layer 2: Abuf[N,256] -> Abuf[N,256] (init after GEMM consumes Abuf)
    gemm_feat<<<gemmG, blk, 0, stream>>>(Abuf, W2, al2, ar2, F, el, er, N, 256, 256, 4);
    init_layer<<<2048, blk, 0, stream>>>(Abuf, b2, N, 256, emax, denom, N * 4);
    edge_scores<4><<<gE, blk, 0, stream>>>(src, dst, el, er, est, emax, E);
    edge_exp<4><<<gE, blk, 0, stream>>>(dst, est, emax, denom, E);
    edge_aggr256<<<gEw, blk, 0, stream>>>(src, dst, est, denom, F, Abuf, E);

    // ---- layer 3: Abuf[N,256] -> out[N,47]
    dim3 gemmG3((N + BM - 1) / BM, 1);
    gemm_feat<<<gemmG3, blk, 0, stream>>>(Abuf, W3, al3, ar3, F, el, er, N, 256, 47, 1);
    init_layer<<<2048, blk, 0, stream>>>(out, b3, N, 47, emax, denom, N * 1);
    edge_scores<1><<<gE, blk, 0, stream>>>(src, dst, el, er, est, emax, E);
    edge_exp<1><<<gE, blk, 0, stream>>>(dst, est, emax, denom, E);
    edge_aggr47<<<gEw, blk, 0, stream>>>(src, dst, est, denom, F, out, E);
}

// Round 2
// 501.445 us; speedup vs baseline: 5.1319x; 5.1319x over previous
//
#include <hip/hip_runtime.h>
#include <cstddef>

#define GAT_N 50000
#define GAT_E 300000

static constexpr int BM = 64, BN = 64, BK = 32;

// ---------------- CSR build ----------------

__global__ __launch_bounds__(256) void zero_ints(int* __restrict__ a, int n) {
    int i = blockIdx.x * blockDim.x + threadIdx.x;
    int stride = gridDim.x * blockDim.x;
    for (; i < n; i += stride) a[i] = 0;
}

__global__ __launch_bounds__(256) void count_k(
    const int* __restrict__ dst, int* __restrict__ cnt, int E)
{
    int e = blockIdx.x * blockDim.x + threadIdx.x;
    if (e < E) atomicAdd(&cnt[dst[e]], 1);
}

// single-workgroup exclusive scan of cnt[0..N) -> rowptr[0..N]
__global__ __launch_bounds__(1024) void scan_k(
    const int* __restrict__ cnt, int* __restrict__ rowptr, int N)
{
    __shared__ int bsum[1024];
    int t = threadIdx.x;
    int per = (N + 1023) / 1024;
    int b = t * per;
    int s = 0;
    for (int i = 0; i < per; ++i) {
        int idx = b + i;
        if (idx < N) s += cnt[idx];
    }
    bsum[t] = s;
    __syncthreads();
    for (int off = 1; off < 1024; off <<= 1) {
        int v = (t >= off) ? bsum[t - off] : 0;
        __syncthreads();
        bsum[t] += v;
        __syncthreads();
    }
    int run = (t == 0) ? 0 : bsum[t - 1];
    for (int i = 0; i < per; ++i) {
        int idx = b + i;
        if (idx <= N) rowptr[idx] = run;
        if (idx < N) run += cnt[idx];
    }
}

__global__ __launch_bounds__(256) void scatter_k(
    const int* __restrict__ src, const int* __restrict__ dst,
    const int* __restrict__ rowptr, int* __restrict__ cursor,
    int* __restrict__ ssrc, int E)
{
    int e = blockIdx.x * blockDim.x + threadIdx.x;
    if (e >= E) return;
    int d = dst[e];
    int p = rowptr[d] + atomicAdd(&cursor[d], 1);
    ssrc[p] = src[e];
}

// ---------------- GEMM + attention-score epilogue ----------------

// feat = A(NxK) @ W(KxM); el[n,h] = sum_d feat*al, er likewise. D = M/H.
__global__ __launch_bounds__(256) void gemm_feat(
    const float* __restrict__ A, const float* __restrict__ W,
    const float* __restrict__ al, const float* __restrict__ ar,
    float* __restrict__ feat, float* __restrict__ el, float* __restrict__ er,
    int N, int K, int M, int H)
{
    __shared__ float As[BK][BM + 4];
    __shared__ float Ws[BK][BN];
    const int m0 = blockIdx.x * BM;
    const int n0 = blockIdx.y * BN;
    const int t  = threadIdx.x;
    const int tx = t & 15, ty = t >> 4;

    float acc[4][4] = {};

    for (int k0 = 0; k0 < K; k0 += BK) {
        #pragma unroll
        for (int l = 0; l < 2; ++l) {
            int i = t + l * 256;
            int row = i >> 3, kk = (i & 7) * 4;
            float4 v = make_float4(0.f, 0.f, 0.f, 0.f);
            int gr = m0 + row;
            if (gr < N) v = *(const float4*)(A + (size_t)gr * K + k0 + kk);
            As[kk + 0][row] = v.x;
            As[kk + 1][row] = v.y;
            As[kk + 2][row] = v.z;
            As[kk + 3][row] = v.w;
        }
        #pragma unroll
        for (int l = 0; l < 2; ++l) {
            int i = t + l * 256;
            int kr = i >> 4, nn = (i & 15) * 4;
            float4 v = make_float4(0.f, 0.f, 0.f, 0.f);
            int gc = n0 + nn;
            const float* wp = W + (size_t)(k0 + kr) * M + gc;
            if (gc + 3 < M) {
                v = *(const float4*)wp;
            } else {
                if (gc + 0 < M) v.x = wp[0];
                if (gc + 1 < M) v.y = wp[1];
                if (gc + 2 < M) v.z = wp[2];
            }
            *(float4*)&Ws[kr][nn] = v;
        }
        __syncthreads();
        #pragma unroll
        for (int k = 0; k < BK; ++k) {
            float av[4], bv[4];
            *(float4*)av = *(const float4*)&As[k][ty * 4];
            *(float4*)bv = *(const float4*)&Ws[k][tx * 4];
            #pragma unroll
            for (int i = 0; i < 4; ++i)
                #pragma unroll
                for (int j = 0; j < 4; ++j)
                    acc[i][j] = fmaf(av[i], bv[j], acc[i][j]);
        }
        __syncthreads();
    }

    const int D = M / H;
    const int head = n0 / D;

    #pragma unroll
    for (int i = 0; i < 4; ++i) {
        int gr = m0 + ty * 4 + i;
        if (gr < N) {
            int gc = n0 + tx * 4;
            if (gc + 3 < M) {
                float4 o = make_float4(acc[i][0], acc[i][1], acc[i][2], acc[i][3]);
                *(float4*)(feat + (size_t)gr * M + gc) = o;
            } else {
                #pragma unroll
                for (int j = 0; j < 4; ++j)
                    if (gc + j < M) feat[(size_t)gr * M + gc + j] = acc[i][j];
            }
        }
    }

    #pragma unroll
    for (int i = 0; i < 4; ++i) {
        float s1 = 0.f, s2 = 0.f;
        #pragma unroll
        for (int j = 0; j < 4; ++j) {
            int gc = n0 + tx * 4 + j;
            if (gc < M) { s1 += acc[i][j] * al[gc]; s2 += acc[i][j] * ar[gc]; }
        }
        #pragma unroll
        for (int mask = 1; mask <= 8; mask <<= 1) {
            s1 += __shfl_xor(s1, mask);
            s2 += __shfl_xor(s2, mask);
        }
        int gr = m0 + ty * 4 + i;
        if (tx == 0 && gr < N) {
            el[(size_t)gr * H + head] = s1;
            er[(size_t)gr * H + head] = s2;
        }
    }
}

// ---------------- fused online-softmax aggregation ----------------

// one wave per dst node; 256 channels = 64 lanes x float4; head = lane>>4
__global__ __launch_bounds__(256) void node_aggr256(
    const int* __restrict__ rowptr, const int* __restrict__ ssrc,
    const float* __restrict__ el, const float* __restrict__ er,
    const float* __restrict__ feat, const float* __restrict__ bias,
    float* __restrict__ out, int N)
{
    int n = blockIdx.x * 4 + (threadIdx.x >> 6);
    if (n >= N) return;
    int lane = threadIdx.x & 63;
    int h = lane >> 4;
    int beg = rowptr[n], end = rowptr[n + 1];
    float erh = er[(size_t)n * 4 + h];
    float m = -__builtin_inff();
    float denom = 0.f;
    float ax = 0.f, ay = 0.f, az = 0.f, aw = 0.f;
    for (int j = beg; j < end; ++j) {
        int s = ssrc[j];
        float sc = el[(size_t)s * 4 + h] + erh;
        sc = sc > 0.f ? sc : 0.2f * sc;
        float w;
        if (sc > m) {
            float r = __expf(m - sc);   // m = -inf on first edge -> r = 0
            denom *= r; ax *= r; ay *= r; az *= r; aw *= r;
            m = sc; w = 1.f;
        } else {
            w = __expf(sc - m);
        }
        denom += w;
        float4 f = *(const float4*)(feat + (size_t)s * 256 + lane * 4);
        ax = fmaf(w, f.x, ax);
        ay = fmaf(w, f.y, ay);
        az = fmaf(w, f.z, az);
        aw = fmaf(w, f.w, aw);
    }
    float inv = 1.f / fmaxf(denom, 1e-9f);
    float4 o;
    o.x = fmaf(ax, inv, bias[lane * 4 + 0]);
    o.y = fmaf(ay, inv, bias[lane * 4 + 1]);
    o.z = fmaf(az, inv, bias[lane * 4 + 2]);
    o.w = fmaf(aw, inv, bias[lane * 4 + 3]);
    *(float4*)(out + (size_t)n * 256 + lane * 4) = o;
}

// one wave per dst node; H=1, D=47; lanes 0..46 hold one channel
__global__ __launch_bounds__(256) void node_aggr47(
    const int* __restrict__ rowptr, const int* __restrict__ ssrc,
    const float* __restrict__ el, const float* __restrict__ er,
    const float* __restrict__ feat, const float* __restrict__ bias,
    float* __restrict__ out, int N)
{
    int n = blockIdx.x * 4 + (threadIdx.x >> 6);
    if (n >= N) return;
    int lane = threadIdx.x & 63;
    int beg = rowptr[n], end = rowptr[n + 1];
    float erh = er[n];
    float m = -__builtin_inff();
    float denom = 0.f;
    float acc = 0.f;
    for (int j = beg; j < end; ++j) {
        int s = ssrc[j];
        float sc = el[s] + erh;
        sc = sc > 0.f ? sc : 0.2f * sc;
        float w;
        if (sc > m) {
            float r = __expf(m - sc);
            denom *= r; acc *= r;
            m = sc; w = 1.f;
        } else {
            w = __expf(sc - m);
        }
        denom += w;
        float f = (lane < 47) ? feat[(size_t)s * 47 + lane] : 0.f;
        acc = fmaf(w, f, acc);
    }
    float inv = 1.f / fmaxf(denom, 1e-9f);
    if (lane < 47)
        out[(size_t)n * 47 + lane] = fmaf(acc, inv, bias[lane]);
}

// ---------------- launch ----------------

extern "C" void kernel_launch(void* const* d_in, const int* in_sizes, int n_in,
                              void* d_out, int out_size, void* d_ws, size_t ws_size,
                              hipStream_t stream) {
    const float* x   = (const float*)d_in[0];
    const int*   src = (const int*)d_in[1];
    const int*   dst = (const int*)d_in[2];
    const float* W1  = (const float*)d_in[3];
    const float* al1 = (const float*)d_in[4];
    const float* ar1 = (const float*)d_in[5];
    const float* b1  = (const float*)d_in[6];
    const float* W2  = (const float*)d_in[7];
    const float* al2 = (const float*)d_in[8];
    const float* ar2 = (const float*)d_in[9];
    const float* b2  = (const float*)d_in[10];
    const float* W3  = (const float*)d_in[11];
    const float* al3 = (const float*)d_in[12];
    const float* ar3 = (const float*)d_in[13];
    const float* b3  = (const float*)d_in[14];
    float* out = (float*)d_out;

    const int N = GAT_N, E = GAT_E;

    char* wsb = (char*)d_ws;
    size_t o = 0;
    float* F     = (float*)(wsb + o); o += (size_t)N * 256 * 4;
    float* Abuf  = (float*)(wsb + o); o += (size_t)N * 256 * 4;
    float* el    = (float*)(wsb + o); o += (size_t)N * 4 * 4;
    float* er    = (float*)(wsb + o); o += (size_t)N * 4 * 4;
    int* rowptr  = (int*)(wsb + o);   o += (size_t)(N + 1) * 4;
    int* cnt     = (int*)(wsb + o);   o += (size_t)N * 4;
    int* cursor  = (int*)(wsb + o);   o += (size_t)N * 4;
    int* ssrc    = (int*)(wsb + o);   o += (size_t)E * 4;

    dim3 blk(256);
    int gE = (E + 255) / 256;
    int gN = (N + 3) / 4;
    dim3 gemmG((N + BM - 1) / BM, 4);
    dim3 gemmG3((N + BM - 1) / BM, 1);

    // ---- CSR build (dst shared by all 3 layers)
    zero_ints<<<256, blk, 0, stream>>>(cnt, N);
    zero_ints<<<256, blk, 0, stream>>>(cursor, N);
    count_k<<<gE, blk, 0, stream>>>(dst, cnt, E);
    scan_k<<<1, 1024, 0, stream>>>(cnt, rowptr, N);
    scatter_k<<<gE, blk, 0, stream>>>(src, dst, rowptr, cursor, ssrc, E);

    // ---- layer 1: x[N,128] -> Abuf[N,256]
    gemm_feat<<<gemmG, blk, 0, stream>>>(x, W1, al1, ar1, F, el, er, N, 128, 256, 4);
    node_aggr256<<<gN, blk, 0, stream>>>(rowptr, ssrc, el, er, F, b1, Abuf, N);

    // ---- layer 2: Abuf[N,256] -> Abuf[N,256]
    gemm_feat<<<gemmG, blk, 0, stream>>>(Abuf, W2, al2, ar2, F, el, er, N, 256, 256, 4);
    node_aggr256<<<gN, blk, 0, stream>>>(rowptr, ssrc, el, er, F, b2, Abuf, N);

    // ---- layer 3: Abuf[N,256] -> out[N,47]
    gemm_feat<<<gemmG3, blk, 0, stream>>>(Abuf, W3, al3, ar3, F, el, er, N, 256, 47, 1);
    node_aggr47<<<gN, blk, 0, stream>>>(rowptr, ssrc, el, er, F, b3, out, N);
}

// Round 3
// 484.243 us; speedup vs baseline: 5.3142x; 1.0355x over previous
//
#include <hip/hip_runtime.h>
#include <cstddef>

#define GAT_N 50000
#define GAT_E 300000

typedef short bf16x8 __attribute__((ext_vector_type(8)));
typedef float f32x4  __attribute__((ext_vector_type(4)));

__device__ __forceinline__ ushort f2bf(float f) {
    unsigned u = __float_as_uint(f);
    return (ushort)((u + 0x7fffu + ((u >> 16) & 1u)) >> 16);
}
__device__ __forceinline__ float bf2f(ushort h) {
    return __uint_as_float((unsigned)h << 16);
}

// ---------------- CSR build ----------------

__global__ __launch_bounds__(256) void zero_ints(int* __restrict__ a, int n) {
    int i = blockIdx.x * blockDim.x + threadIdx.x;
    int stride = gridDim.x * blockDim.x;
    for (; i < n; i += stride) a[i] = 0;
}

__global__ __launch_bounds__(256) void count_k(
    const int* __restrict__ dst, int* __restrict__ cnt, int E)
{
    int e = blockIdx.x * blockDim.x + threadIdx.x;
    if (e < E) atomicAdd(&cnt[dst[e]], 1);
}

__global__ __launch_bounds__(1024) void scan_k(
    const int* __restrict__ cnt, int* __restrict__ rowptr, int N)
{
    __shared__ int bsum[1024];
    int t = threadIdx.x;
    int per = (N + 1023) / 1024;
    int b = t * per;
    int s = 0;
    for (int i = 0; i < per; ++i) {
        int idx = b + i;
        if (idx < N) s += cnt[idx];
    }
    bsum[t] = s;
    __syncthreads();
    for (int off = 1; off < 1024; off <<= 1) {
        int v = (t >= off) ? bsum[t - off] : 0;
        __syncthreads();
        bsum[t] += v;
        __syncthreads();
    }
    int run = (t == 0) ? 0 : bsum[t - 1];
    for (int i = 0; i < per; ++i) {
        int idx = b + i;
        if (idx <= N) rowptr[idx] = run;
        if (idx < N) run += cnt[idx];
    }
}

__global__ __launch_bounds__(256) void scatter_k(
    const int* __restrict__ src, const int* __restrict__ dst,
    const int* __restrict__ rowptr, int* __restrict__ cursor,
    int* __restrict__ ssrc, int E)
{
    int e = blockIdx.x * blockDim.x + threadIdx.x;
    if (e >= E) return;
    int d = dst[e];
    int p = rowptr[d] + atomicAdd(&cursor[d], 1);
    ssrc[p] = src[e];
}

// ---------------- bf16x3 split-precision MFMA GEMM + score epilogue ----------------
// feat[N,M] = A[N,K] @ W[K,M]; el[n,h]=sum_d feat*al, er likewise.
// 64x64 block, BK=32, 4 waves x (16 rows x 64 cols). K % 32 == 0.

#define LDK 40   // 32 + 8 pad (ushorts): row stride 80B -> 2-way (free) banking

__global__ __launch_bounds__(256) void gemm_feat(
    const float* __restrict__ A, const float* __restrict__ W,
    const float* __restrict__ al, const float* __restrict__ ar,
    float* __restrict__ feat, float* __restrict__ el, float* __restrict__ er,
    int N, int K, int M, int H)
{
    __shared__ ushort As_h[64 * LDK];
    __shared__ ushort As_l[64 * LDK];
    __shared__ ushort Ws_h[64 * LDK];
    __shared__ ushort Ws_l[64 * LDK];

    const int m0 = blockIdx.x * 64;
    const int n0 = blockIdx.y * 64;
    const int t  = threadIdx.x;
    const int w    = t >> 6;
    const int lane = t & 63;
    const int lr   = lane & 15;
    const int lg   = lane >> 4;

    f32x4 acc[4] = {};

    for (int k0 = 0; k0 < K; k0 += 32) {
        // stage A: 64 rows x 32 k, fp32 -> bf16 hi/lo
        #pragma unroll
        for (int l = 0; l < 2; ++l) {
            int idx = t + l * 256;
            int row = idx >> 3, kk = (idx & 7) * 4;
            float4 v = make_float4(0.f, 0.f, 0.f, 0.f);
            int gr = m0 + row;
            if (gr < N) v = *(const float4*)(A + (size_t)gr * K + k0 + kk);
            ushort4 h, lo;
            h.x = f2bf(v.x); lo.x = f2bf(v.x - bf2f(h.x));
            h.y = f2bf(v.y); lo.y = f2bf(v.y - bf2f(h.y));
            h.z = f2bf(v.z); lo.z = f2bf(v.z - bf2f(h.z));
            h.w = f2bf(v.w); lo.w = f2bf(v.w - bf2f(h.w));
            *(ushort4*)&As_h[row * LDK + kk] = h;
            *(ushort4*)&As_l[row * LDK + kk] = lo;
        }
        // stage W transposed: Ws[n][k]
        #pragma unroll
        for (int l = 0; l < 2; ++l) {
            int idx = t + l * 256;
            int kr = idx >> 4, nn = (idx & 15) * 4;
            const float* wp = W + (size_t)(k0 + kr) * M + n0 + nn;
            #pragma unroll
            for (int c = 0; c < 4; ++c) {
                int gc = n0 + nn + c;
                float v = (gc < M) ? wp[c] : 0.f;
                ushort h = f2bf(v);
                ushort lo = f2bf(v - bf2f(h));
                Ws_h[(nn + c) * LDK + kr] = h;
                Ws_l[(nn + c) * LDK + kr] = lo;
            }
        }
        __syncthreads();

        bf16x8 ah  = *(const bf16x8*)&As_h[(w * 16 + lr) * LDK + 8 * lg];
        bf16x8 alo = *(const bf16x8*)&As_l[(w * 16 + lr) * LDK + 8 * lg];
        #pragma unroll
        for (int j = 0; j < 4; ++j) {
            bf16x8 bh = *(const bf16x8*)&Ws_h[(j * 16 + lr) * LDK + 8 * lg];
            bf16x8 bl = *(const bf16x8*)&Ws_l[(j * 16 + lr) * LDK + 8 * lg];
            acc[j] = __builtin_amdgcn_mfma_f32_16x16x32_bf16(ah,  bh, acc[j], 0, 0, 0);
            acc[j] = __builtin_amdgcn_mfma_f32_16x16x32_bf16(alo, bh, acc[j], 0, 0, 0);
            acc[j] = __builtin_amdgcn_mfma_f32_16x16x32_bf16(ah,  bl, acc[j], 0, 0, 0);
        }
        __syncthreads();
    }

    // D[row = 4*lg + r][col = lr] per 16x16 frag j (cols j*16..j*16+15)
    const int head = n0 >> 6;

    #pragma unroll
    for (int j = 0; j < 4; ++j) {
        int col = n0 + j * 16 + lr;
        if (col < M) {
            #pragma unroll
            for (int r = 0; r < 4; ++r) {
                int row = m0 + w * 16 + 4 * lg + r;
                if (row < N) feat[(size_t)row * M + col] = acc[j][r];
            }
        }
    }

    float alv[4], arv[4];
    #pragma unroll
    for (int j = 0; j < 4; ++j) {
        int col = n0 + j * 16 + lr;
        alv[j] = (col < M) ? al[col] : 0.f;
        arv[j] = (col < M) ? ar[col] : 0.f;
    }
    #pragma unroll
    for (int r = 0; r < 4; ++r) {
        float s1 = 0.f, s2 = 0.f;
        #pragma unroll
        for (int j = 0; j < 4; ++j) {
            s1 = fmaf(acc[j][r], alv[j], s1);
            s2 = fmaf(acc[j][r], arv[j], s2);
        }
        #pragma unroll
        for (int mask = 1; mask <= 8; mask <<= 1) {
            s1 += __shfl_xor(s1, mask);
            s2 += __shfl_xor(s2, mask);
        }
        int row = m0 + w * 16 + 4 * lg + r;
        if (lr == 0 && row < N) {
            el[(size_t)row * H + head] = s1;
            er[(size_t)row * H + head] = s2;
        }
    }
}

// ---------------- fused softmax aggregation (2-pass, branch-free accumulate) ----------------

__global__ __launch_bounds__(256) void node_aggr256(
    const int* __restrict__ rowptr, const int* __restrict__ ssrc,
    const float* __restrict__ el, const float* __restrict__ er,
    const float* __restrict__ feat, const float* __restrict__ bias,
    float* __restrict__ out, int N)
{
    int n = blockIdx.x * 4 + (threadIdx.x >> 6);
    if (n >= N) return;
    int lane = threadIdx.x & 63;
    int h = lane >> 4;
    int beg = rowptr[n], end = rowptr[n + 1];
    float erh = er[(size_t)n * 4 + h];

    float m = -__builtin_inff();
    for (int j = beg; j < end; ++j) {
        float sc = el[(size_t)ssrc[j] * 4 + h] + erh;
        sc = sc > 0.f ? sc : 0.2f * sc;
        m = fmaxf(m, sc);
    }

    float denom = 0.f;
    float ax = 0.f, ay = 0.f, az = 0.f, aw = 0.f;
    for (int j = beg; j < end; ++j) {
        int s = ssrc[j];
        float sc = el[(size_t)s * 4 + h] + erh;
        sc = sc > 0.f ? sc : 0.2f * sc;
        float wgt = __expf(sc - m);
        denom += wgt;
        float4 f = *(const float4*)(feat + (size_t)s * 256 + lane * 4);
        ax = fmaf(wgt, f.x, ax);
        ay = fmaf(wgt, f.y, ay);
        az = fmaf(wgt, f.z, az);
        aw = fmaf(wgt, f.w, aw);
    }
    float inv = 1.f / fmaxf(denom, 1e-9f);
    float4 o;
    o.x = fmaf(ax, inv, bias[lane * 4 + 0]);
    o.y = fmaf(ay, inv, bias[lane * 4 + 1]);
    o.z = fmaf(az, inv, bias[lane * 4 + 2]);
    o.w = fmaf(aw, inv, bias[lane * 4 + 3]);
    *(float4*)(out + (size_t)n * 256 + lane * 4) = o;
}

__global__ __launch_bounds__(256) void node_aggr47(
    const int* __restrict__ rowptr, const int* __restrict__ ssrc,
    const float* __restrict__ el, const float* __restrict__ er,
    const float* __restrict__ feat, const float* __restrict__ bias,
    float* __restrict__ out, int N)
{
    int n = blockIdx.x * 4 + (threadIdx.x >> 6);
    if (n >= N) return;
    int lane = threadIdx.x & 63;
    int beg = rowptr[n], end = rowptr[n + 1];
    float erh = er[n];

    float m = -__builtin_inff();
    for (int j = beg; j < end; ++j) {
        float sc = el[ssrc[j]] + erh;
        sc = sc > 0.f ? sc : 0.2f * sc;
        m = fmaxf(m, sc);
    }

    float denom = 0.f, acc = 0.f;
    for (int j = beg; j < end; ++j) {
        int s = ssrc[j];
        float sc = el[s] + erh;
        sc = sc > 0.f ? sc : 0.2f * sc;
        float wgt = __expf(sc - m);
        denom += wgt;
        float f = (lane < 47) ? feat[(size_t)s * 47 + lane] : 0.f;
        acc = fmaf(wgt, f, acc);
    }
    float inv = 1.f / fmaxf(denom, 1e-9f);
    if (lane < 47)
        out[(size_t)n * 47 + lane] = fmaf(acc, inv, bias[lane]);
}

// ---------------- launch ----------------

extern "C" void kernel_launch(void* const* d_in, const int* in_sizes, int n_in,
                              void* d_out, int out_size, void* d_ws, size_t ws_size,
                              hipStream_t stream) {
    const float* x   = (const float*)d_in[0];
    const int*   src = (const int*)d_in[1];
    const int*   dst = (const int*)d_in[2];
    const float* W1  = (const float*)d_in[3];
    const float* al1 = (const float*)d_in[4];
    const float* ar1 = (const float*)d_in[5];
    const float* b1  = (const float*)d_in[6];
    const float* W2  = (const float*)d_in[7];
    const float* al2 = (const float*)d_in[8];
    const float* ar2 = (const float*)d_in[9];
    const float* b2  = (const float*)d_in[10];
    const float* W3  = (const float*)d_in[11];
    const float* al3 = (const float*)d_in[12];
    const float* ar3 = (const float*)d_in[13];
    const float* b3  = (const float*)d_in[14];
    float* out = (float*)d_out;

    const int N = GAT_N, E = GAT_E;

    char* wsb = (char*)d_ws;
    size_t o = 0;
    float* F     = (float*)(wsb + o); o += (size_t)N * 256 * 4;
    float* Abuf  = (float*)(wsb + o); o += (size_t)N * 256 * 4;
    float* el    = (float*)(wsb + o); o += (size_t)N * 4 * 4;
    float* er    = (float*)(wsb + o); o += (size_t)N * 4 * 4;
    int* rowptr  = (int*)(wsb + o);   o += (size_t)(N + 1) * 4;
    int* cnt     = (int*)(wsb + o);   o += (size_t)N * 4;
    int* cursor  = (int*)(wsb + o);   o += (size_t)N * 4;
    int* ssrc    = (int*)(wsb + o);   o += (size_t)E * 4;

    dim3 blk(256);
    int gE = (E + 255) / 256;
    int gN = (N + 3) / 4;
    dim3 gemmG((N + 63) / 64, 4);
    dim3 gemmG3((N + 63) / 64, 1);

    // ---- CSR build (dst shared by all 3 layers)
    zero_ints<<<256, blk, 0, stream>>>(cnt, N);
    zero_ints<<<256, blk, 0, stream>>>(cursor, N);
    count_k<<<gE, blk, 0, stream>>>(dst, cnt, E);
    scan_k<<<1, 1024, 0, stream>>>(cnt, rowptr, N);
    scatter_k<<<gE, blk, 0, stream>>>(src, dst, rowptr, cursor, ssrc, E);

    // ---- layer 1: x[N,128] -> Abuf[N,256]
    gemm_feat<<<gemmG, blk, 0, stream>>>(x, W1, al1, ar1, F, el, er, N, 128, 256, 4);
    node_aggr256<<<gN, blk, 0, stream>>>(rowptr, ssrc, el, er, F, b1, Abuf, N);

    // ---- layer 2: Abuf[N,256] -> Abuf[N,256]
    gemm_feat<<<gemmG, blk, 0, stream>>>(Abuf, W2, al2, ar2, F, el, er, N, 256, 256, 4);
    node_aggr256<<<gN, blk, 0, stream>>>(rowptr, ssrc, el, er, F, b2, Abuf, N);

    // ---- layer 3: Abuf[N,256] -> out[N,47]
    gemm_feat<<<gemmG3, blk, 0, stream>>>(Abuf, W3, al3, ar3, F, el, er, N, 256, 47, 1);
    node_aggr47<<<gN, blk, 0, stream>>>(rowptr, ssrc, el, er, F, b3, out, N);
}

// Round 4
// 351.265 us; speedup vs baseline: 7.3260x; 1.3786x over previous
//
#include <hip/hip_runtime.h>
#include <cstddef>

#define GAT_N 50000
#define GAT_E 300000
#define SCAN_B 256

typedef short bf16x8 __attribute__((ext_vector_type(8)));
typedef float f32x4  __attribute__((ext_vector_type(4)));

__device__ __forceinline__ ushort f2bf(float f) {
    unsigned u = __float_as_uint(f);
    return (ushort)((u + 0x7fffu + ((u >> 16) & 1u)) >> 16);
}
__device__ __forceinline__ float bf2f(ushort h) {
    return __uint_as_float((unsigned)h << 16);
}

// ---------------- CSR build ----------------

__global__ __launch_bounds__(256) void zero_ints(int* __restrict__ a, int n) {
    int i = blockIdx.x * blockDim.x + threadIdx.x;
    int stride = gridDim.x * blockDim.x;
    for (; i < n; i += stride) a[i] = 0;
}

__global__ __launch_bounds__(256) void count_k(
    const int* __restrict__ dst, int* __restrict__ cnt, int E)
{
    int e = blockIdx.x * blockDim.x + threadIdx.x;
    if (e < E) atomicAdd(&cnt[dst[e]], 1);
}

// block b sums cnt[b*chunk .. b*chunk+chunk) -> partials[b]
__global__ __launch_bounds__(256) void csr_partial(
    const int* __restrict__ cnt, int* __restrict__ partials, int N, int chunk)
{
    __shared__ int red[256];
    int b = blockIdx.x, t = threadIdx.x;
    int s = 0;
    for (int i = t; i < chunk; i += 256) {
        int idx = b * chunk + i;
        if (idx < N) s += cnt[idx];
    }
    red[t] = s;
    __syncthreads();
    for (int off = 128; off > 0; off >>= 1) {
        if (t < off) red[t] += red[t + off];
        __syncthreads();
    }
    if (t == 0) partials[b] = red[0];
}

// single block: exclusive-scan partials[SCAN_B] in place; write rowptr[N]=total
__global__ __launch_bounds__(SCAN_B) void csr_scanp(
    int* __restrict__ partials, int* __restrict__ rowptr, int N)
{
    __shared__ int sc[SCAN_B];
    int t = threadIdx.x;
    int v = partials[t];
    sc[t] = v;
    __syncthreads();
    for (int off = 1; off < SCAN_B; off <<= 1) {
        int u = (t >= off) ? sc[t - off] : 0;
        __syncthreads();
        sc[t] += u;
        __syncthreads();
    }
    partials[t] = sc[t] - v;            // exclusive
    if (t == SCAN_B - 1) rowptr[N] = sc[t];
}

// block b: exclusive scan of its chunk, offset by partials[b]
__global__ __launch_bounds__(256) void csr_write(
    const int* __restrict__ cnt, const int* __restrict__ partials,
    int* __restrict__ rowptr, int N, int chunk)
{
    __shared__ int sc[256];
    int b = blockIdx.x, t = threadIdx.x;
    int idx = b * chunk + t;                    // chunk <= 256
    int v = (t < chunk && idx < N) ? cnt[idx] : 0;
    sc[t] = v;
    __syncthreads();
    for (int off = 1; off < 256; off <<= 1) {
        int u = (t >= off) ? sc[t - off] : 0;
        __syncthreads();
        sc[t] += u;
        __syncthreads();
    }
    if (t < chunk && idx < N) rowptr[idx] = partials[b] + sc[t] - v;
}

__global__ __launch_bounds__(256) void scatter_k(
    const int* __restrict__ src, const int* __restrict__ dst,
    const int* __restrict__ rowptr, int* __restrict__ cursor,
    int* __restrict__ ssrc, int E)
{
    int e = blockIdx.x * blockDim.x + threadIdx.x;
    if (e >= E) return;
    int d = dst[e];
    int p = rowptr[d] + atomicAdd(&cursor[d], 1);
    ssrc[p] = src[e];
}

// ---------------- precision-split converts ----------------

// x [N][K] fp32 -> Xh/Xl bf16 (row-major, same layout)
__global__ __launch_bounds__(256) void convert_x(
    const float* __restrict__ x, ushort* __restrict__ Xh, ushort* __restrict__ Xl,
    long total4)
{
    long i = (long)blockIdx.x * blockDim.x + threadIdx.x;
    long stride = (long)gridDim.x * blockDim.x;
    for (; i < total4; i += stride) {
        float4 v = *(const float4*)(x + i * 4);
        ushort4 h, lo;
        h.x = f2bf(v.x); lo.x = f2bf(v.x - bf2f(h.x));
        h.y = f2bf(v.y); lo.y = f2bf(v.y - bf2f(h.y));
        h.z = f2bf(v.z); lo.z = f2bf(v.z - bf2f(h.z));
        h.w = f2bf(v.w); lo.w = f2bf(v.w - bf2f(h.w));
        *(ushort4*)(Xh + i * 4) = h;
        *(ushort4*)(Xl + i * 4) = lo;
    }
}

// W [K][M] fp32 -> Wt_h/Wt_l [Mp][K] bf16 (transposed, zero-padded cols >= M)
__global__ __launch_bounds__(256) void convert_w(
    const float* __restrict__ W, ushort* __restrict__ Wth, ushort* __restrict__ Wtl,
    int K, int M, int Mp)
{
    int idx = blockIdx.x * blockDim.x + threadIdx.x;
    if (idx >= Mp * K) return;
    int c = idx / K, k = idx - c * K;
    float v = (c < M) ? W[(size_t)k * M + c] : 0.f;
    ushort h = f2bf(v);
    Wth[idx] = h;
    Wtl[idx] = f2bf(v - bf2f(h));
}

// ---------------- bf16x3 MFMA GEMM + score epilogue ----------------
// feat[N,M] = A[N,K] @ W[K,M] with A,B pre-split bf16 hi/lo; Wt is [Mp][K].
// 128x128 block, BK=32, 4 waves (2x2) each 64x64 via 4x4 frags of 16x16x32.

#define LDK 40   // 32 + 8 pad ushorts: 80B row stride -> 2-way (free) banks

__global__ __launch_bounds__(256) void gemm_feat(
    const ushort* __restrict__ Ah, const ushort* __restrict__ Al,
    const ushort* __restrict__ Wh, const ushort* __restrict__ Wl,
    const float* __restrict__ alw, const float* __restrict__ arw,
    float* __restrict__ feat, float* __restrict__ el, float* __restrict__ er,
    int N, int K, int M, int H, int D)
{
    __shared__ ushort As_h[128 * LDK];
    __shared__ ushort As_l[128 * LDK];
    __shared__ ushort Bs_h[128 * LDK];
    __shared__ ushort Bs_l[128 * LDK];

    const int m0 = blockIdx.x * 128;
    const int n0 = blockIdx.y * 128;
    const int t = threadIdx.x;
    const int w = t >> 6, lane = t & 63;
    const int lr = lane & 15, lg = lane >> 4;
    const int wr = (w >> 1) * 64, wc = (w & 1) * 64;

    f32x4 acc[4][4] = {};

    for (int k0 = 0; k0 < K; k0 += 32) {
        #pragma unroll
        for (int l = 0; l < 2; ++l) {
            int idx = t + l * 256;
            int row = idx >> 2, kk = (idx & 3) * 8;
            bf16x8 vh = {}, vl = {};
            int gr = m0 + row;
            if (gr < N) {
                vh = *(const bf16x8*)(Ah + (size_t)gr * K + k0 + kk);
                vl = *(const bf16x8*)(Al + (size_t)gr * K + k0 + kk);
            }
            bf16x8 wh = *(const bf16x8*)(Wh + (size_t)(n0 + row) * K + k0 + kk);
            bf16x8 wl = *(const bf16x8*)(Wl + (size_t)(n0 + row) * K + k0 + kk);
            *(bf16x8*)&As_h[row * LDK + kk] = vh;
            *(bf16x8*)&As_l[row * LDK + kk] = vl;
            *(bf16x8*)&Bs_h[row * LDK + kk] = wh;
            *(bf16x8*)&Bs_l[row * LDK + kk] = wl;
        }
        __syncthreads();

        bf16x8 a_h[4], a_l[4];
        #pragma unroll
        for (int fi = 0; fi < 4; ++fi) {
            a_h[fi] = *(const bf16x8*)&As_h[(wr + fi * 16 + lr) * LDK + lg * 8];
            a_l[fi] = *(const bf16x8*)&As_l[(wr + fi * 16 + lr) * LDK + lg * 8];
        }
        #pragma unroll
        for (int fj = 0; fj < 4; ++fj) {
            bf16x8 b_h = *(const bf16x8*)&Bs_h[(wc + fj * 16 + lr) * LDK + lg * 8];
            bf16x8 b_l = *(const bf16x8*)&Bs_l[(wc + fj * 16 + lr) * LDK + lg * 8];
            #pragma unroll
            for (int fi = 0; fi < 4; ++fi) {
                acc[fi][fj] = __builtin_amdgcn_mfma_f32_16x16x32_bf16(a_h[fi], b_h, acc[fi][fj], 0, 0, 0);
                acc[fi][fj] = __builtin_amdgcn_mfma_f32_16x16x32_bf16(a_l[fi], b_h, acc[fi][fj], 0, 0, 0);
                acc[fi][fj] = __builtin_amdgcn_mfma_f32_16x16x32_bf16(a_h[fi], b_l, acc[fi][fj], 0, 0, 0);
            }
        }
        __syncthreads();
    }

    // C/D: row = 4*lg + q, col = lr (verified layout)
    #pragma unroll
    for (int fi = 0; fi < 4; ++fi) {
        #pragma unroll
        for (int q = 0; q < 4; ++q) {
            int row = m0 + wr + fi * 16 + 4 * lg + q;
            if (row < N) {
                #pragma unroll
                for (int fj = 0; fj < 4; ++fj) {
                    int col = n0 + wc + fj * 16 + lr;
                    if (col < M) feat[(size_t)row * M + col] = acc[fi][fj][q];
                }
            }
        }
    }

    const int head = (n0 + wc) / D;
    if (head < H) {
        float alv[4], arv[4];
        #pragma unroll
        for (int fj = 0; fj < 4; ++fj) {
            int col = n0 + wc + fj * 16 + lr;
            alv[fj] = (col < M) ? alw[col] : 0.f;
            arv[fj] = (col < M) ? arw[col] : 0.f;
        }
        #pragma unroll
        for (int fi = 0; fi < 4; ++fi) {
            #pragma unroll
            for (int q = 0; q < 4; ++q) {
                float s1 = 0.f, s2 = 0.f;
                #pragma unroll
                for (int fj = 0; fj < 4; ++fj) {
                    s1 = fmaf(acc[fi][fj][q], alv[fj], s1);
                    s2 = fmaf(acc[fi][fj][q], arv[fj], s2);
                }
                #pragma unroll
                for (int mask = 1; mask <= 8; mask <<= 1) {
                    s1 += __shfl_xor(s1, mask);
                    s2 += __shfl_xor(s2, mask);
                }
                int row = m0 + wr + fi * 16 + 4 * lg + q;
                if (lr == 0 && row < N) {
                    el[(size_t)row * H + head] = s1;
                    er[(size_t)row * H + head] = s2;
                }
            }
        }
    }
}

// ---------------- fused softmax aggregation (2-pass) ----------------

// one wave per dst node; writes bf16 hi/lo for the next GEMM's A operand
__global__ __launch_bounds__(256) void node_aggr256(
    const int* __restrict__ rowptr, const int* __restrict__ ssrc,
    const float* __restrict__ el, const float* __restrict__ er,
    const float* __restrict__ feat, const float* __restrict__ bias,
    ushort* __restrict__ Ah_out, ushort* __restrict__ Al_out, int N)
{
    int n = blockIdx.x * 4 + (threadIdx.x >> 6);
    if (n >= N) return;
    int lane = threadIdx.x & 63;
    int h = lane >> 4;
    int beg = rowptr[n], end = rowptr[n + 1];
    float erh = er[(size_t)n * 4 + h];

    float m = -__builtin_inff();
    for (int j = beg; j < end; ++j) {
        float sc = el[(size_t)ssrc[j] * 4 + h] + erh;
        sc = sc > 0.f ? sc : 0.2f * sc;
        m = fmaxf(m, sc);
    }

    float denom = 0.f;
    float ax = 0.f, ay = 0.f, az = 0.f, aw = 0.f;
    for (int j = beg; j < end; ++j) {
        int s = ssrc[j];
        float sc = el[(size_t)s * 4 + h] + erh;
        sc = sc > 0.f ? sc : 0.2f * sc;
        float wgt = __expf(sc - m);
        denom += wgt;
        float4 f = *(const float4*)(feat + (size_t)s * 256 + lane * 4);
        ax = fmaf(wgt, f.x, ax);
        ay = fmaf(wgt, f.y, ay);
        az = fmaf(wgt, f.z, az);
        aw = fmaf(wgt, f.w, aw);
    }
    float inv = 1.f / fmaxf(denom, 1e-9f);
    float v0 = fmaf(ax, inv, bias[lane * 4 + 0]);
    float v1 = fmaf(ay, inv, bias[lane * 4 + 1]);
    float v2 = fmaf(az, inv, bias[lane * 4 + 2]);
    float v3 = fmaf(aw, inv, bias[lane * 4 + 3]);
    ushort4 hh, lo;
    hh.x = f2bf(v0); lo.x = f2bf(v0 - bf2f(hh.x));
    hh.y = f2bf(v1); lo.y = f2bf(v1 - bf2f(hh.y));
    hh.z = f2bf(v2); lo.z = f2bf(v2 - bf2f(hh.z));
    hh.w = f2bf(v3); lo.w = f2bf(v3 - bf2f(hh.w));
    *(ushort4*)(Ah_out + (size_t)n * 256 + lane * 4) = hh;
    *(ushort4*)(Al_out + (size_t)n * 256 + lane * 4) = lo;
}

__global__ __launch_bounds__(256) void node_aggr47(
    const int* __restrict__ rowptr, const int* __restrict__ ssrc,
    const float* __restrict__ el, const float* __restrict__ er,
    const float* __restrict__ feat, const float* __restrict__ bias,
    float* __restrict__ out, int N)
{
    int n = blockIdx.x * 4 + (threadIdx.x >> 6);
    if (n >= N) return;
    int lane = threadIdx.x & 63;
    int beg = rowptr[n], end = rowptr[n + 1];
    float erh = er[n];

    float m = -__builtin_inff();
    for (int j = beg; j < end; ++j) {
        float sc = el[ssrc[j]] + erh;
        sc = sc > 0.f ? sc : 0.2f * sc;
        m = fmaxf(m, sc);
    }

    float denom = 0.f, acc = 0.f;
    for (int j = beg; j < end; ++j) {
        int s = ssrc[j];
        float sc = el[s] + erh;
        sc = sc > 0.f ? sc : 0.2f * sc;
        float wgt = __expf(sc - m);
        denom += wgt;
        float f = (lane < 47) ? feat[(size_t)s * 47 + lane] : 0.f;
        acc = fmaf(wgt, f, acc);
    }
    float inv = 1.f / fmaxf(denom, 1e-9f);
    if (lane < 47)
        out[(size_t)n * 47 + lane] = fmaf(acc, inv, bias[lane]);
}

// ---------------- launch ----------------

extern "C" void kernel_launch(void* const* d_in, const int* in_sizes, int n_in,
                              void* d_out, int out_size, void* d_ws, size_t ws_size,
                              hipStream_t stream) {
    const float* x   = (const float*)d_in[0];
    const int*   src = (const int*)d_in[1];
    const int*   dst = (const int*)d_in[2];
    const float* W1  = (const float*)d_in[3];
    const float* al1 = (const float*)d_in[4];
    const float* ar1 = (const float*)d_in[5];
    const float* b1  = (const float*)d_in[6];
    const float* W2  = (const float*)d_in[7];
    const float* al2 = (const float*)d_in[8];
    const float* ar2 = (const float*)d_in[9];
    const float* b2  = (const float*)d_in[10];
    const float* W3  = (const float*)d_in[11];
    const float* al3 = (const float*)d_in[12];
    const float* ar3 = (const float*)d_in[13];
    const float* b3  = (const float*)d_in[14];
    float* out = (float*)d_out;

    const int N = GAT_N, E = GAT_E;
    const int chunk = (N + SCAN_B - 1) / SCAN_B;   // 196

    char* wsb = (char*)d_ws;
    size_t o = 0;
    float*  feat  = (float*)(wsb + o);  o += (size_t)N * 256 * 4;
    ushort* Ah    = (ushort*)(wsb + o); o += (size_t)N * 256 * 2;   // also aliases Xh [N][128]
    ushort* Al    = (ushort*)(wsb + o); o += (size_t)N * 256 * 2;   // also aliases Xl
    float*  el    = (float*)(wsb + o);  o += (size_t)N * 4 * 4;
    float*  er    = (float*)(wsb + o);  o += (size_t)N * 4 * 4;
    int* rowptr   = (int*)(wsb + o);    o += (size_t)(N + 1) * 4;
    int* cnt      = (int*)(wsb + o);    o += (size_t)N * 4;
    int* cursor   = (int*)(wsb + o);    o += (size_t)N * 4;         // contiguous after cnt
    int* ssrc     = (int*)(wsb + o);    o += (size_t)E * 4;
    int* partials = (int*)(wsb + o);    o += (size_t)SCAN_B * 4;
    ushort* Wt1h  = (ushort*)(wsb + o); o += (size_t)256 * 128 * 2;
    ushort* Wt1l  = (ushort*)(wsb + o); o += (size_t)256 * 128 * 2;
    ushort* Wt2h  = (ushort*)(wsb + o); o += (size_t)256 * 256 * 2;
    ushort* Wt2l  = (ushort*)(wsb + o); o += (size_t)256 * 256 * 2;
    ushort* Wt3h  = (ushort*)(wsb + o); o += (size_t)128 * 256 * 2;
    ushort* Wt3l  = (ushort*)(wsb + o); o += (size_t)128 * 256 * 2;
    ushort* Xh = Ah;   // [N][128] alias, dead after gemm1
    ushort* Xl = Al;

    dim3 blk(256);
    int gE = (E + 255) / 256;
    int gN = (N + 3) / 4;
    dim3 gemmG((N + 127) / 128, 2);
    dim3 gemmG3((N + 127) / 128, 1);

    // ---- CSR build
    zero_ints<<<64, blk, 0, stream>>>(cnt, 2 * N);          // cnt + cursor
    count_k<<<gE, blk, 0, stream>>>(dst, cnt, E);
    csr_partial<<<SCAN_B, blk, 0, stream>>>(cnt, partials, N, chunk);
    csr_scanp<<<1, SCAN_B, 0, stream>>>(partials, rowptr, N);
    csr_write<<<SCAN_B, blk, 0, stream>>>(cnt, partials, rowptr, N, chunk);
    scatter_k<<<gE, blk, 0, stream>>>(src, dst, rowptr, cursor, ssrc, E);

    // ---- weight / input converts
    convert_x<<<2048, blk, 0, stream>>>(x, Xh, Xl, (long)N * 128 / 4);
    convert_w<<<(256 * 128 + 255) / 256, blk, 0, stream>>>(W1, Wt1h, Wt1l, 128, 256, 256);
    convert_w<<<(256 * 256 + 255) / 256, blk, 0, stream>>>(W2, Wt2h, Wt2l, 256, 256, 256);
    convert_w<<<(128 * 256 + 255) / 256, blk, 0, stream>>>(W3, Wt3h, Wt3l, 256, 47, 128);

    // ---- layer 1: x[N,128] -> Ah/Al[N,256]
    gemm_feat<<<gemmG, blk, 0, stream>>>(Xh, Xl, Wt1h, Wt1l, al1, ar1,
                                         feat, el, er, N, 128, 256, 4, 64);
    node_aggr256<<<gN, blk, 0, stream>>>(rowptr, ssrc, el, er, feat, b1, Ah, Al, N);

    // ---- layer 2
    gemm_feat<<<gemmG, blk, 0, stream>>>(Ah, Al, Wt2h, Wt2l, al2, ar2,
                                         feat, el, er, N, 256, 256, 4, 64);
    node_aggr256<<<gN, blk, 0, stream>>>(rowptr, ssrc, el, er, feat, b2, Ah, Al, N);

    // ---- layer 3: -> out[N,47]
    gemm_feat<<<gemmG3, blk, 0, stream>>>(Ah, Al, Wt3h, Wt3l, al3, ar3,
                                          feat, el, er, N, 256, 47, 1, 47);
    node_aggr47<<<gN, blk, 0, stream>>>(rowptr, ssrc, el, er, feat, b3, out, N);
}